// Round 10
// baseline (323.801 us; speedup 1.0000x reference)
//
#include <hip/hip_runtime.h>
#include <hip/hip_bf16.h>
#include <stdint.h>

#define IN_F   4096
#define OUT_F  4096
#define M_ROWS 2048
#define LORA_SCALE 2.0f   // 32.0 / 16

typedef __bf16 bf16x8 __attribute__((ext_vector_type(8)));
typedef float  f32x4  __attribute__((ext_vector_type(4)));

typedef const __attribute__((address_space(1))) void gvoid_t;
typedef __attribute__((address_space(3))) void lvoid_t;

// s_waitcnt imm: vmcnt[3:0]|[15:14], expcnt[6:4]=7 (nowait), lgkmcnt[11:8]=15 (nowait)
#define WAITVM(n) __builtin_amdgcn_s_waitcnt(((n)&0xF) | (((n)>>4)<<14) | (7<<4) | (15<<8))

// ---------- 1a. repack: qw int32 (ONE byte / elem: 2 nibbles = 2 weights in
// 4 bytes) -> true-packed nibble stream qp (8.4 MB). Weight k of row n ->
// bit 4*(k%8) of qp[n*512 + k/8]. Replaces the dequant kernel: 42 MB traffic
// instead of 67 MB, and lets the GEMM stage B 4x denser.
__global__ void repack_kernel(const int* __restrict__ qw,
                              uint32_t* __restrict__ qp) {
    int t = blockIdx.x * 256 + threadIdx.x;        // 524288 threads
    const int4* src = (const int4*)qw + 4 * (size_t)t;
    int4 a = src[0], b = src[1], c = src[2], d = src[3];
    uint4 o;
    o.x = (uint32_t)(a.x & 255) | ((uint32_t)(a.y & 255) << 8) |
          ((uint32_t)(a.z & 255) << 16) | ((uint32_t)(a.w & 255) << 24);
    o.y = (uint32_t)(b.x & 255) | ((uint32_t)(b.y & 255) << 8) |
          ((uint32_t)(b.z & 255) << 16) | ((uint32_t)(b.w & 255) << 24);
    o.z = (uint32_t)(c.x & 255) | ((uint32_t)(c.y & 255) << 8) |
          ((uint32_t)(c.z & 255) << 16) | ((uint32_t)(c.w & 255) << 24);
    o.w = (uint32_t)(d.x & 255) | ((uint32_t)(d.y & 255) << 8) |
          ((uint32_t)(d.z & 255) << 16) | ((uint32_t)(d.w & 255) << 24);
    ((uint4*)qp)[t] = o;
}

// ---------- 1b. x cast f32 -> bf16 (proven; unchanged)
__global__ void xcast_kernel(const float* __restrict__ x,
                             __hip_bfloat16* __restrict__ xb) {
    int t = blockIdx.x * 256 + threadIdx.x;
    float4 a = ((const float4*)x)[2*t];
    float4 c = ((const float4*)x)[2*t + 1];
    union { __hip_bfloat16 h[8]; uint4 v; } o;
    o.h[0] = __float2bfloat16(a.x); o.h[1] = __float2bfloat16(a.y);
    o.h[2] = __float2bfloat16(a.z); o.h[3] = __float2bfloat16(a.w);
    o.h[4] = __float2bfloat16(c.x); o.h[5] = __float2bfloat16(c.y);
    o.h[6] = __float2bfloat16(c.z); o.h[7] = __float2bfloat16(c.w);
    ((uint4*)xb)[t] = o.v;
}

// ---------- 1c. lora t = x @ A^T  [2048,16] (proven; unchanged).
// R9 lesson: do NOT fuse the xb store in here (divergent store in the
// latency-bound loop cost ~40 us; the duplicate x read is cache-resident).
__global__ void lora_kernel(const float* __restrict__ x,
                            const float* __restrict__ A,
                            float* __restrict__ tout) {
    __shared__ float red[16 * 4 * 16];
    int m0 = blockIdx.x * 4;
    int r = threadIdx.x & 15;
    int g = threadIdx.x >> 4;
    float acc[4] = {0.f, 0.f, 0.f, 0.f};
    const float* ar = A + (size_t)r * IN_F;
    for (int kb = 0; kb < 32; ++kb) {
        int k = kb * 128 + g * 8;
        float4 a0 = *(const float4*)(ar + k);
        float4 a1 = *(const float4*)(ar + k + 4);
        #pragma unroll
        for (int row = 0; row < 4; ++row) {
            float4 x0 = *(const float4*)(x + (size_t)(m0 + row) * IN_F + k);
            float4 x1 = *(const float4*)(x + (size_t)(m0 + row) * IN_F + k + 4);
            acc[row] += x0.x*a0.x + x0.y*a0.y + x0.z*a0.z + x0.w*a0.w
                      + x1.x*a1.x + x1.y*a1.y + x1.z*a1.z + x1.w*a1.w;
        }
    }
    #pragma unroll
    for (int row = 0; row < 4; ++row) red[g*64 + row*16 + r] = acc[row];
    __syncthreads();
    if (threadIdx.x < 64) {
        int row = threadIdx.x >> 4, rr = threadIdx.x & 15;
        float s = 0.f;
        #pragma unroll
        for (int gg = 0; gg < 16; ++gg) s += red[gg*64 + row*16 + rr];
        tout[(size_t)(m0 + row) * 16 + rr] = s;
    }
}

// ---------- 2. DEQUANT-FUSED GEMM. R7 skeleton preserved exactly: 4 waves,
// 128x128 tile, BK=32, 4 stages, prefetch dist 3, counted WAITVM(8)/4/0
// (still 4 loads/wave/slab: 2x A size-16 + 2x B size-4), raw s_barrier,
// XCD swizzle. NEW: B staged as packed nibbles (2 KB/slab vs 8 KB; staged
// bytes/slab 16->10 KB on a staging-BW-bound kernel), panel scales (32 KB)
// preloaded to LDS once, nibble->bf16 expansion in-register with the SAME
// arithmetic as the proven dequant kernel (fma(idx, s*2/15, -s), then
// __float2bfloat16). LDS 32+8+32 = 72 KB -> still 2 blocks/CU.
// Bank math: packed-B ds_read (row16*4+quad)%32 -> 2-way (free, no XOR);
// scl read [kblk*128+row] -> 16 banks + quad-broadcast (free).
__global__ __launch_bounds__(256) void gemm_kernel(
        const __hip_bfloat16* __restrict__ A,     // [M, K] bf16
        const uint32_t* __restrict__ Bq,          // [N, K/8] packed nibbles
        const float* __restrict__ scales,         // [N*64] row-major [row][kblk]
        const float* __restrict__ bias,           // [N]
        const float* __restrict__ loraB,          // [N, 16]
        const float* __restrict__ tmat,           // [M, 16]
        float* __restrict__ out) {                // [M, N]
    const int K = IN_F, N = OUT_F;
    __shared__ union alignas(16) {
        struct {
            __hip_bfloat16 As[4][128*32];   // 32 KB
            uint32_t       Bp[4][128*4];    //  8 KB (128 rows x 16 B packed)
            float          scl[64*128];     // 32 KB  [kblk][row]
        } s;
        float tl[128 * 16];                 // 8 KB, overlaps As[0] only
    } sm;

    int tid  = threadIdx.x;
    int wave = tid >> 6, lane = tid & 63;
    int wm = wave >> 1, wn = wave & 1;            // 2x2 wave grid over 128x128
    int row16 = lane & 15, quad = lane >> 4;

    // XCD swizzle (part of the R7-measured artifact)
    int lin = blockIdx.y * 32 + blockIdx.x;
    int xcd = lin & 7, slot = lin >> 3;
    int bx = (xcd & 3) * 8 + (slot & 7);
    int by = (xcd >> 2) * 8 + (slot >> 3);
    int m0 = by * 128, n0 = bx * 128;

    // A DMA mapping (verified): lane i -> row rl=i>>2 of 16-row segment,
    // global 16B-chunk cg=(i&3)^((rl>>1)&3); LDS lands at base + lane*16.
    int rl = lane >> 2;
    int cg = (lane & 3) ^ ((rl >> 1) & 3);

    const __hip_bfloat16* pA0 = A + (size_t)(m0 + wave*32 + rl) * K + cg*8;
    const __hip_bfloat16* pA1 = pA0 + (size_t)16 * K;
    // B packed DMA: size-4 loads, lane i -> row i>>2, u32-chunk i&3 (linear,
    // no XOR needed). LDS dest = base + lane*4.
    const uint32_t* pB0 = Bq + (size_t)(n0 + wave*32 + rl) * 512 + (lane & 3);
    const uint32_t* pB1 = pB0 + (size_t)16 * 512;

    // ---- one-time: panel scales -> LDS, transposed to [kblk][row]
    {
        const float* sg = scales + (size_t)n0 * 64;   // 128 rows x 64 kblks
        int r2 = tid >> 1;              // row 0..127 (2 threads/row)
        int c2 = (tid & 1) * 32;        // kblk half
        const float* src = sg + (size_t)r2 * 64 + c2;
        #pragma unroll
        for (int j = 0; j < 32; j += 4) {
            float4 v = *(const float4*)(src + j);
            sm.s.scl[(c2 + j + 0)*128 + r2] = v.x;
            sm.s.scl[(c2 + j + 1)*128 + r2] = v.y;
            sm.s.scl[(c2 + j + 2)*128 + r2] = v.z;
            sm.s.scl[(c2 + j + 3)*128 + r2] = v.w;
        }
    }
    __syncthreads();

    f32x4 acc[4][4];
    #pragma unroll
    for (int i = 0; i < 4; ++i)
        #pragma unroll
        for (int j = 0; j < 4; ++j) acc[i][j] = (f32x4){0.f, 0.f, 0.f, 0.f};

    float scl_r[4], step_r[4];

    // refresh per-lane scales for k-block kb (changes every 2 slabs)
    #define SCALES(kb)                                                            \
        _Pragma("unroll")                                                         \
        for (int nt = 0; nt < 4; ++nt) {                                          \
            float sv = sm.s.scl[(kb)*128 + wn*64 + nt*16 + row16];                \
            scl_r[nt] = sv; step_r[nt] = sv * (2.0f / 15.0f);                     \
        }

    // stage next slab into stage `buf` (4 loads/wave: 2 A + 2 B), advance
    #define DMA(buf)                                                              \
        __builtin_amdgcn_global_load_lds((gvoid_t*)pA0, (lvoid_t*)&sm.s.As[buf][(wave*2+0)*512], 16, 0, 0); \
        __builtin_amdgcn_global_load_lds((gvoid_t*)pA1, (lvoid_t*)&sm.s.As[buf][(wave*2+1)*512], 16, 0, 0); \
        __builtin_amdgcn_global_load_lds((gvoid_t*)pB0, (lvoid_t*)&sm.s.Bp[buf][wave*128],      4, 0, 0);  \
        __builtin_amdgcn_global_load_lds((gvoid_t*)pB1, (lvoid_t*)&sm.s.Bp[buf][wave*128 + 64], 4, 0, 0);  \
        pA0 += 32; pA1 += 32; pB0 += 4; pB1 += 4;

    // one 16x16x32 k-step: A fragments as before; B fragments expanded from
    // packed nibbles with the proven dequant arithmetic.
    #define COMPUTE(buf)                                                          \
    {                                                                             \
        bf16x8 af[4], bfr[4];                                                     \
        _Pragma("unroll")                                                         \
        for (int mt = 0; mt < 4; ++mt) {                                          \
            int row = wm*64 + mt*16 + row16;                                      \
            af[mt] = *(const bf16x8*)&sm.s.As[buf][row*32 + ((quad ^ ((row>>1)&3)) << 3)]; \
        }                                                                         \
        _Pragma("unroll")                                                         \
        for (int nt = 0; nt < 4; ++nt) {                                          \
            int row = wn*64 + nt*16 + row16;                                      \
            uint32_t pw = sm.s.Bp[buf][row*4 + quad];                             \
            float st = step_r[nt], sc = scl_r[nt];                                \
            union { __hip_bfloat16 h[8]; bf16x8 v; } u;                           \
            _Pragma("unroll")                                                     \
            for (int j = 0; j < 8; ++j)                                           \
                u.h[j] = __float2bfloat16(                                        \
                    fmaf((float)((pw >> (4*j)) & 15u), st, -sc));                 \
            bfr[nt] = u.v;                                                        \
        }                                                                         \
        _Pragma("unroll")                                                         \
        for (int mt = 0; mt < 4; ++mt)                                            \
            _Pragma("unroll")                                                     \
            for (int nt = 0; nt < 4; ++nt)                                        \
                acc[mt][nt] = __builtin_amdgcn_mfma_f32_16x16x32_bf16(            \
                    af[mt], bfr[nt], acc[mt][nt], 0, 0, 0);                       \
    }

    // one pipeline step: consume slab in stage p, prefetch into stage (p+3)&3
    #define STEP(p)                                                               \
        WAITVM(8);                         /* own slab-i loads retired */         \
        __builtin_amdgcn_s_barrier();      /* all waves ditto => slab i in LDS */ \
        __builtin_amdgcn_sched_barrier(0);                                        \
        COMPUTE(p)                                                                \
        DMA((p+3)&3)

    // prologue: slabs 0,1,2 -> stages 0,1,2 (12 loads/wave outstanding)
    DMA(0)
    DMA(1)
    DMA(2)

    // main: group u consumes slabs 4u..4u+3 (k-blocks 2u,2u,2u+1,2u+1)
    for (int u = 0; u < 31; ++u) {
        SCALES(2*u)
        STEP(0)
        STEP(1)
        SCALES(2*u + 1)
        STEP(2)
        STEP(3)
    }
    // tail: slabs 124..127 (kblocks 62,62,63,63)
    SCALES(62)
    STEP(0)
    WAITVM(8); __builtin_amdgcn_s_barrier(); __builtin_amdgcn_sched_barrier(0);
    COMPUTE(1)
    SCALES(63)
    WAITVM(4); __builtin_amdgcn_s_barrier(); __builtin_amdgcn_sched_barrier(0);
    COMPUTE(2)
    WAITVM(0); __builtin_amdgcn_s_barrier(); __builtin_amdgcn_sched_barrier(0);
    COMPUTE(3)

    #undef STEP
    #undef COMPUTE
    #undef DMA
    #undef SCALES

    // fused epilogue. tl overlaps As[0] only (final COMPUTE(3) reads stage 3;
    // scl/Bp live elsewhere in the union).
    #pragma unroll
    for (int i = 0; i < 2; ++i)
        ((float4*)sm.tl)[tid + i*256] =
            ((const float4*)(tmat + (size_t)m0 * 16))[tid + i*256];
    __syncthreads();

    #pragma unroll
    for (int nt = 0; nt < 4; ++nt) {
        int n = n0 + wn*64 + nt*16 + row16;
        float bn = bias[n];
        const float4* lb = (const float4*)(loraB + (size_t)n * 16);
        float4 b0 = lb[0], b1 = lb[1], b2 = lb[2], b3 = lb[3];
        #pragma unroll
        for (int mt = 0; mt < 4; ++mt) {
            #pragma unroll
            for (int r = 0; r < 4; ++r) {
                int ml = wm*64 + mt*16 + quad*4 + r;
                const float* tm = &sm.tl[ml * 16];
                float dot =
                    tm[0]*b0.x + tm[1]*b0.y + tm[2]*b0.z + tm[3]*b0.w +
                    tm[4]*b1.x + tm[5]*b1.y + tm[6]*b1.z + tm[7]*b1.w +
                    tm[8]*b2.x + tm[9]*b2.y + tm[10]*b2.z + tm[11]*b2.w +
                    tm[12]*b3.x + tm[13]*b3.y + tm[14]*b3.z + tm[15]*b3.w;
                out[(size_t)(m0 + ml) * N + n] = acc[mt][nt][r] + bn + LORA_SCALE * dot;
            }
        }
    }
}

extern "C" void kernel_launch(void* const* d_in, const int* in_sizes, int n_in,
                              void* d_out, int out_size, void* d_ws, size_t ws_size,
                              hipStream_t stream) {
    const float* x      = (const float*)d_in[0];   // [2,1024,4096]
    const int*   qw     = (const int*)d_in[1];     // [8388608] one byte each
    const float* scales = (const float*)d_in[2];   // [262144]
    const float* bias   = (const float*)d_in[3];   // [4096]
    const float* loraA  = (const float*)d_in[4];   // [16,4096]
    const float* loraB  = (const float*)d_in[5];   // [4096,16]
    float* out = (float*)d_out;

    char* ws = (char*)d_ws;
    uint32_t* qp       = (uint32_t*)ws;                       //  8,388,608 B (in old Wb slot)
    __hip_bfloat16* Xb = (__hip_bfloat16*)(ws + 33554432);    // 16,777,216 B
    float* tmat        = (float*)(ws + 50331648);             //    131,072 B

    repack_kernel<<<2048, 256, 0, stream>>>(qw, qp);
    xcast_kernel<<<4096, 256, 0, stream>>>(x, Xb);
    lora_kernel<<<512, 256, 0, stream>>>(x, loraA, tmat);
    gemm_kernel<<<dim3(32, 16), 256, 0, stream>>>(Xb, qp, scales, bias, loraB, tmat, out);
}